// Round 1
// baseline (104.775 us; speedup 1.0000x reference)
//
#include <hip/hip_runtime.h>
#include <math.h>

#define NQ 6
#define NLAYERS 2
#define ROW_D 512

// One wave64 per batch row: lane i holds complex amplitude i of the 64-dim
// statevector. All quantum gates are cross-lane shuffles:
//   - qubit q's bit sits at position (5-q) of the amplitude index (qubit 0 is
//     the most-significant axis in the reference), so a 1-qubit gate on q
//     pairs lanes differing in mask 1<<(5-q)  -> __shfl_xor.
//   - CNOT(c,t) is a conditional permutation: lane takes the value from
//     lane ^ (1<<(5-t)) iff its control bit is 1.
__global__ __launch_bounds__(256) void qlayer_kernel(
    const float* __restrict__ x, const float* __restrict__ W,
    const float* __restrict__ bvec, const float* __restrict__ weights,
    float* __restrict__ out, int B)
{
    // Precompute the 12 Rot(phi,theta,omega) matrices (batch-independent)
    // once per block into LDS. 8 floats per gate: u00,u01,u10,u11 (re,im).
    __shared__ float gmat[NLAYERS * NQ * 8];
    const int tid = threadIdx.x;
    if (tid < NLAYERS * NQ) {
        float phi = weights[tid * 3 + 0];
        float th  = weights[tid * 3 + 1];
        float om  = weights[tid * 3 + 2];
        float ct = cosf(0.5f * th), st = sinf(0.5f * th);
        float A  = 0.5f * (phi + om);
        float Bb = 0.5f * (phi - om);
        float cA = cosf(A), sA = sinf(A);
        float cB = cosf(Bb), sB = sinf(Bb);
        float* g = &gmat[tid * 8];
        g[0] =  cA * ct;  g[1] = -sA * ct;   // u00 = exp(-i(phi+om)/2) * ct
        g[2] = -cB * st;  g[3] = -sB * st;   // u01 = -exp(i(phi-om)/2) * st
        g[4] =  cB * st;  g[5] = -sB * st;   // u10 =  conj(em) * st
        g[6] =  cA * ct;  g[7] =  sA * ct;   // u11 =  conj(ep) * ct
    }
    __syncthreads();

    const int lane = tid & 63;
    const int wave = tid >> 6;
    const int b = blockIdx.x * 4 + wave;
    if (b >= B) return;

    // ---- z = x[b] @ W^T + bias: 16B/lane coalesced x loads, wave reduce ----
    const float4* xr = reinterpret_cast<const float4*>(x + (size_t)b * ROW_D);
    const float4 xa = xr[lane];
    const float4 xb = xr[lane + 64];
    float z[NQ];
    #pragma unroll
    for (int r = 0; r < NQ; ++r) {
        const float4* wr = reinterpret_cast<const float4*>(W + r * ROW_D);
        float4 wa = wr[lane];
        float4 wb = wr[lane + 64];
        float p = xa.x * wa.x + xa.y * wa.y + xa.z * wa.z + xa.w * wa.w
                + xb.x * wb.x + xb.y * wb.y + xb.z * wb.z + xb.w * wb.w;
        #pragma unroll
        for (int m = 32; m >= 1; m >>= 1)
            p += __shfl_xor(p, m, 64);
        z[r] = p + bvec[r];
    }

    // ---- L2 normalize -> RX rotation angles ----
    float n2 = 0.f;
    #pragma unroll
    for (int r = 0; r < NQ; ++r) n2 += z[r] * z[r];
    const float inv = rsqrtf(n2);

    // ---- statevector init: |000000> ----
    float sr = (lane == 0) ? 1.f : 0.f;
    float si = 0.f;

    // ---- AngleEmbedding: RX(angle_q) on each qubit ----
    // RX: new_a = ct*a - i*st*partner  (symmetric for both bit values)
    #pragma unroll
    for (int q = 0; q < NQ; ++q) {
        float half = 0.5f * z[q] * inv;
        float st, ct;
        __sincosf(half, &st, &ct);
        const int m = 1 << (5 - q);
        float pr = __shfl_xor(sr, m, 64);
        float pi = __shfl_xor(si, m, 64);
        float nr = ct * sr + st * pi;     // -i*st*(pr+i*pi) = st*pi - i*st*pr
        float ni = ct * si - st * pr;
        sr = nr; si = ni;
    }

    // ---- StronglyEntanglingLayers ----
    #pragma unroll
    for (int l = 0; l < NLAYERS; ++l) {
        #pragma unroll
        for (int q = 0; q < NQ; ++q) {
            const float* g = &gmat[(l * NQ + q) * 8];
            const int bit = (lane >> (5 - q)) & 1;
            const int m = 1 << (5 - q);
            float pr = __shfl_xor(sr, m, 64);
            float pi = __shfl_xor(si, m, 64);
            // diag coeff (multiplies own amplitude), off coeff (times partner)
            float dr = bit ? g[6] : g[0];
            float di = bit ? g[7] : g[1];
            float er = bit ? g[4] : g[2];
            float ei = bit ? g[5] : g[3];
            float nr = dr * sr - di * si + er * pr - ei * pi;
            float ni = dr * si + di * sr + er * pi + ei * pr;
            sr = nr; si = ni;
        }
        const int rng = (l % (NQ - 1)) + 1;   // layer 0: r=1, layer 1: r=2
        #pragma unroll
        for (int q = 0; q < NQ; ++q) {
            const int t = (q + rng) % NQ;
            const int mt = 1 << (5 - t);
            const int cbit = (lane >> (5 - q)) & 1;
            float vr = __shfl_xor(sr, mt, 64);
            float vi = __shfl_xor(si, mt, 64);
            sr = cbit ? vr : sr;
            si = cbit ? vi : si;
        }
    }

    // ---- probs -> <Z_q> per qubit, wave reductions ----
    const float p = sr * sr + si * si;
    float e0, e1, e2, e3, e4, e5;
    #pragma unroll
    for (int q = 0; q < NQ; ++q) {
        float v = ((lane >> (5 - q)) & 1) ? -p : p;
        #pragma unroll
        for (int m = 32; m >= 1; m >>= 1)
            v += __shfl_xor(v, m, 64);
        if (q == 0) e0 = v; else if (q == 1) e1 = v; else if (q == 2) e2 = v;
        else if (q == 3) e3 = v; else if (q == 4) e4 = v; else e5 = v;
    }

    float r = e0;
    if (lane == 1) r = e1;
    if (lane == 2) r = e2;
    if (lane == 3) r = e3;
    if (lane == 4) r = e4;
    if (lane == 5) r = e5;
    if (lane < NQ) out[(size_t)b * NQ + lane] = r;
}

extern "C" void kernel_launch(void* const* d_in, const int* in_sizes, int n_in,
                              void* d_out, int out_size, void* d_ws, size_t ws_size,
                              hipStream_t stream) {
    const float* x  = (const float*)d_in[0];
    const float* W  = (const float*)d_in[1];
    const float* bv = (const float*)d_in[2];
    const float* wt = (const float*)d_in[3];
    float* out = (float*)d_out;
    const int B = in_sizes[0] / ROW_D;
    const int blocks = (B + 3) / 4;   // 4 waves (rows) per 256-thread block
    qlayer_kernel<<<blocks, 256, 0, stream>>>(x, W, bv, wt, out, B);
}

// Round 2
// 49.931 us; speedup vs baseline: 2.0984x; 2.0984x over previous
//
#include <hip/hip_runtime.h>
#include <math.h>

#define NQ 6
#define NLAYERS 2
#define ROW_D 512

// wave-uniform broadcast from a fixed lane (v_readlane: VALU, no LDS pipe)
__device__ __forceinline__ float bcastf(float v, int srclane) {
    return __int_as_float(__builtin_amdgcn_readlane(__float_as_int(v), srclane));
}

// Butterfly level that merges two accumulators: after the call, lanes with
// (lane&m)==0 hold u_l + u_{l^m}; lanes with (lane&m)==1 hold v_l + v_{l^m}.
__device__ __forceinline__ float merge_red(float u, float v, int m, int lane) {
    float send = (lane & m) ? u : v;       // send what the partner needs
    float recv = __shfl_xor(send, m, 64);
    return ((lane & m) ? v : u) + recv;
}

__global__ __launch_bounds__(256) void qlayer_kernel(
    const float* __restrict__ x, const float* __restrict__ W,
    const float* __restrict__ bvec, const float* __restrict__ weights,
    float* __restrict__ out, int B)
{
    // 12 Rot matrices, batch-independent. Layout per gate (8 floats, two 16B
    // chunks selected by the lane's qubit bit):
    //   chunk bit=0: {u00r,u00i,u01r,u01i}   chunk bit=1: {u11r,u11i,u10r,u10i}
    __shared__ __align__(16) float gmat[NLAYERS * NQ * 8];
    const int tid = threadIdx.x;
    if (tid < NLAYERS * NQ) {
        float phi = weights[tid * 3 + 0];
        float th  = weights[tid * 3 + 1];
        float om  = weights[tid * 3 + 2];
        float st, ct, sA, cA, sB, cB;
        __sincosf(0.5f * th, &st, &ct);
        __sincosf(0.5f * (phi + om), &sA, &cA);
        __sincosf(0.5f * (phi - om), &sB, &cB);
        float* g = &gmat[tid * 8];
        g[0] =  cA * ct;  g[1] = -sA * ct;   // u00 = e^{-iA} ct
        g[2] = -cB * st;  g[3] = -sB * st;   // u01 = -e^{iB} st
        g[4] =  cA * ct;  g[5] =  sA * ct;   // u11 = e^{iA} ct
        g[6] =  cB * st;  g[7] = -sB * st;   // u10 = e^{-iB} st
    }
    __syncthreads();

    const int lane = tid & 63;
    const int wave = tid >> 6;
    const int b = blockIdx.x * 4 + wave;
    if (b >= B) return;

    // ---- 6 partial dot products, 8 elems/lane, coalesced 16B loads ----
    const float4* xr = reinterpret_cast<const float4*>(x + (size_t)b * ROW_D);
    const float4 xa = xr[lane];
    const float4 xb = xr[lane + 64];
    float p[NQ];
    #pragma unroll
    for (int r = 0; r < NQ; ++r) {
        const float4* wr = reinterpret_cast<const float4*>(W + r * ROW_D);
        float4 wa = wr[lane];
        float4 wb = wr[lane + 64];
        p[r] = xa.x * wa.x + xa.y * wa.y + xa.z * wa.z + xa.w * wa.w
             + xb.x * wb.x + xb.y * wb.y + xb.z * wb.z + xb.w * wb.w;
    }

    // ---- merged butterfly reduce: 9 shuffles for all 6 sums ----
    // slot map (lane&7): 0..5 -> z0..z5, 6 -> z4, 7 -> z5 (duplicates)
    float A_ = merge_red(p[0], p[1], 1, lane);
    float Bm = merge_red(p[2], p[3], 1, lane);
    float C  = merge_red(p[4], p[5], 1, lane);
    float D_ = merge_red(A_, Bm, 2, lane);
    C += __shfl_xor(C, 2, 64);
    float E  = merge_red(D_, C, 4, lane);
    E += __shfl_xor(E, 8, 64);
    E += __shfl_xor(E, 16, 64);
    E += __shfl_xor(E, 32, 64);

    const int o = lane & 7;
    const int slot = (o < 6) ? o : (o - 2);
    E += bvec[slot];

    // ---- norm over the 6 distinct slots (each octet holds all 6) ----
    float sq = (o < 6) ? E * E : 0.f;
    sq += __shfl_xor(sq, 1, 64);
    sq += __shfl_xor(sq, 2, 64);
    sq += __shfl_xor(sq, 4, 64);
    const float ang = 0.5f * E * rsqrtf(sq);   // this lane's slot half-angle
    float s_ang, c_ang;
    __sincosf(ang, &s_ang, &c_ang);

    // ---- AngleEmbedding as a tensor product (no shuffles):
    // amp(l) = prod_q (bit ? s_q : c_q) * (-i)^popc(l)
    float mag = 1.f;
    #pragma unroll
    for (int q = 0; q < NQ; ++q) {
        float cq = bcastf(c_ang, q);   // lane q's slot is q
        float sq_ = bcastf(s_ang, q);
        mag *= ((lane >> (5 - q)) & 1) ? sq_ : cq;
    }
    const int pc = __popc(lane);
    const float magn = (pc & 2) ? -mag : mag;
    float sr = (pc & 1) ? 0.f : magn;
    float si = (pc & 1) ? ((pc & 2) ? mag : -mag) : 0.f;

    // ---- compose each layer's CNOT ring into ONE lane permutation ----
    // s_final[l] = s_0[P_1(P_2(...P_6(l)))]  (apply last gate's perm first)
    int srcA = lane;
    #pragma unroll
    for (int q = NQ - 1; q >= 0; --q) {
        const int t = (q + 1) % NQ;                       // layer 0: r=1
        srcA ^= ((srcA >> (5 - q)) & 1) << (5 - t);
    }
    int srcB = lane;
    #pragma unroll
    for (int q = NQ - 1; q >= 0; --q) {
        const int t = (q + 2) % NQ;                       // layer 1: r=2
        srcB ^= ((srcB >> (5 - q)) & 1) << (5 - t);
    }
    const int adA = srcA << 2, adB = srcB << 2;

    // ---- StronglyEntanglingLayers ----
    #pragma unroll
    for (int l = 0; l < NLAYERS; ++l) {
        #pragma unroll
        for (int q = 0; q < NQ; ++q) {
            const int bp = 5 - q, m = 1 << bp;
            const int bit = (lane >> bp) & 1;
            const float4 g = *reinterpret_cast<const float4*>(
                &gmat[((l * NQ + q) << 3) + (bit << 2)]);
            float pr = __shfl_xor(sr, m, 64);
            float pi = __shfl_xor(si, m, 64);
            float nr = g.x * sr - g.y * si + g.z * pr - g.w * pi;
            float ni = g.x * si + g.y * sr + g.z * pi + g.w * pr;
            sr = nr; si = ni;
        }
        const int ad = (l == 0) ? adA : adB;
        sr = __int_as_float(__builtin_amdgcn_ds_bpermute(ad, __float_as_int(sr)));
        si = __int_as_float(__builtin_amdgcn_ds_bpermute(ad, __float_as_int(si)));
    }

    // ---- all 6 expvals via one Walsh-Hadamard butterfly ----
    // lane k = 1<<(5-q) ends holding  sum_l (-1)^{bit_{5-q}(l)} p_l = <Z_q>
    float pv = sr * sr + si * si;
    #pragma unroll
    for (int m = 1; m <= 32; m <<= 1) {
        float t = __shfl_xor(pv, m, 64);
        pv = (lane & m) ? (t - pv) : (pv + t);
    }
    if (__popc(lane) == 1) {
        const int k = 31 - __clz(lane);          // lane = 2^k  ->  qubit 5-k
        out[(size_t)b * NQ + (5 - k)] = pv;
    }
}

extern "C" void kernel_launch(void* const* d_in, const int* in_sizes, int n_in,
                              void* d_out, int out_size, void* d_ws, size_t ws_size,
                              hipStream_t stream) {
    const float* x  = (const float*)d_in[0];
    const float* W  = (const float*)d_in[1];
    const float* bv = (const float*)d_in[2];
    const float* wt = (const float*)d_in[3];
    float* out = (float*)d_out;
    const int B = in_sizes[0] / ROW_D;
    const int blocks = (B + 3) / 4;   // 4 waves (rows) per 256-thread block
    qlayer_kernel<<<blocks, 256, 0, stream>>>(x, W, bv, wt, out, B);
}

// Round 3
// 38.395 us; speedup vs baseline: 2.7289x; 1.3005x over previous
//
#include <hip/hip_runtime.h>
#include <math.h>

#define NQ 6
#define NLAYERS 2
#define ROW_D 512

typedef short short8 __attribute__((ext_vector_type(8)));   // 8 bf16 in 4 VGPRs
typedef float f32x4 __attribute__((ext_vector_type(4)));

__device__ __forceinline__ ushort f2bf(float f) {           // f32 -> bf16 (RNE)
    unsigned u = __float_as_uint(f);
    return (ushort)((u + 0x7fffu + ((u >> 16) & 1u)) >> 16);
}

__device__ __forceinline__ float bcastf(float v, int srclane) {
    return __int_as_float(__builtin_amdgcn_readlane(__float_as_int(v), srclane));
}

// Merged butterfly level: lanes with (lane&m)==0 end with u_l+u_{l^m},
// lanes with (lane&m)==1 end with v_l+v_{l^m}.
__device__ __forceinline__ float merge_red(float u, float v, int m, int lane) {
    float send = (lane & m) ? u : v;
    float recv = __shfl_xor(send, m, 64);
    return ((lane & m) ? v : u) + recv;
}

// ---------------- Kernel 1: build U' = Circuit * diag((-i)^popc(j)) --------
// One wave simulates one basis column j through 12 Rot + 2 CNOT-ring perms.
// Stores U'_re / U'_im as 64x64 bf16 row-major (row = output idx i, col = j).
__global__ __launch_bounds__(256) void gen_unitary(
    const float* __restrict__ weights, ushort* __restrict__ Mws)
{
    __shared__ __align__(16) float gmat[NLAYERS * NQ * 8];
    const int tid = threadIdx.x;
    if (tid < NLAYERS * NQ) {
        float phi = weights[tid * 3 + 0];
        float th  = weights[tid * 3 + 1];
        float om  = weights[tid * 3 + 2];
        float st, ct, sA, cA, sB, cB;
        __sincosf(0.5f * th, &st, &ct);
        __sincosf(0.5f * (phi + om), &sA, &cA);
        __sincosf(0.5f * (phi - om), &sB, &cB);
        float* g = &gmat[tid * 8];
        g[0] =  cA * ct;  g[1] = -sA * ct;   // u00
        g[2] = -cB * st;  g[3] = -sB * st;   // u01
        g[4] =  cA * ct;  g[5] =  sA * ct;   // u11
        g[6] =  cB * st;  g[7] = -sB * st;   // u10
    }
    __syncthreads();

    const int lane = tid & 63;
    const int wave = tid >> 6;
    const int jj = blockIdx.x * 4 + wave;    // 16 blocks x 4 waves = 64 columns

    // compose each layer's CNOT ring into one lane permutation
    int srcA = lane;
    #pragma unroll
    for (int q = NQ - 1; q >= 0; --q) {
        const int t = (q + 1) % NQ;
        srcA ^= ((srcA >> (5 - q)) & 1) << (5 - t);
    }
    int srcB = lane;
    #pragma unroll
    for (int q = NQ - 1; q >= 0; --q) {
        const int t = (q + 2) % NQ;
        srcB ^= ((srcB >> (5 - q)) & 1) << (5 - t);
    }
    const int adA = srcA << 2, adB = srcB << 2;

    float sr = (lane == jj) ? 1.f : 0.f;
    float si = 0.f;
    #pragma unroll
    for (int l = 0; l < NLAYERS; ++l) {
        #pragma unroll
        for (int q = 0; q < NQ; ++q) {
            const int bp = 5 - q, m = 1 << bp;
            const int bit = (lane >> bp) & 1;
            const float4 g = *reinterpret_cast<const float4*>(
                &gmat[((l * NQ + q) << 3) + (bit << 2)]);
            float pr = __shfl_xor(sr, m, 64);
            float pi = __shfl_xor(si, m, 64);
            float nr = g.x * sr - g.y * si + g.z * pr - g.w * pi;
            float ni = g.x * si + g.y * sr + g.z * pi + g.w * pr;
            sr = nr; si = ni;
        }
        const int ad = (l == 0) ? adA : adB;
        sr = __int_as_float(__builtin_amdgcn_ds_bpermute(ad, __float_as_int(sr)));
        si = __int_as_float(__builtin_amdgcn_ds_bpermute(ad, __float_as_int(si)));
    }

    // fold column phase (-i)^popc(jj)  (wave-uniform branch)
    const int pc = __popc(jj) & 3;
    float r2, i2;
    if      (pc == 1) { r2 =  si; i2 = -sr; }
    else if (pc == 2) { r2 = -sr; i2 = -si; }
    else if (pc == 3) { r2 = -si; i2 =  sr; }
    else              { r2 =  sr; i2 =  si; }
    Mws[lane * 64 + jj]        = f2bf(r2);   // U'_re[i=lane][j=jj]
    Mws[4096 + lane * 64 + jj] = f2bf(i2);   // U'_im
}

// ---------------- Kernel 2: GEMV -> w -> MFMA -> expvals -------------------
__global__ __launch_bounds__(256) void qmain(
    const float* __restrict__ x, const float* __restrict__ W,
    const float* __restrict__ bvec, const ushort* __restrict__ Mws,
    float* __restrict__ out, int B)
{
    // LDS: U' (both matrices, XOR-chunk-swizzled) + wave-private w tiles
    __shared__ short8 Mlds[2][64][8];     // 16 KB
    __shared__ short8 wtile[4][16][8];    //  8 KB
    const int tid = threadIdx.x;

    // stage U' global->LDS with chunk swizzle c ^= (row&7)
    const short8* mg = reinterpret_cast<const short8*>(Mws);
    #pragma unroll
    for (int i = 0; i < 4; ++i) {
        const int idx = tid + i * 256;                // 1024 chunks of 16B
        short8 v = mg[idx];
        const int mat = idx >> 9, row = (idx >> 3) & 63, c = idx & 7;
        Mlds[mat][row][c ^ (row & 7)] = v;
    }
    __syncthreads();

    const int lane = tid & 63;
    const int wave = tid >> 6;
    const int rowbase = blockIdx.x * 64 + wave * 16;

    // W resident in VGPRs (48 regs) — loaded ONCE per wave, not per row
    float4 wv0[NQ], wv1[NQ];
    #pragma unroll
    for (int r = 0; r < NQ; ++r) {
        const float4* wr = reinterpret_cast<const float4*>(W + r * ROW_D);
        wv0[r] = wr[lane];
        wv1[r] = wr[lane + 64];
    }
    const int o = lane & 7;
    const int slot = (o < 6) ? o : (o - 2);
    const float bv = bvec[slot];

    ushort* wp = (ushort*)&wtile[wave][0][0];

    // ---- phase A: 16 rows, GEMV + angles + product-state w -> LDS ----
    #pragma unroll 4
    for (int r16 = 0; r16 < 16; ++r16) {
        const float4* xr = reinterpret_cast<const float4*>(
            x + (size_t)(rowbase + r16) * ROW_D);
        const float4 xa = xr[lane];
        const float4 xb = xr[lane + 64];
        float p[NQ];
        #pragma unroll
        for (int r = 0; r < NQ; ++r) {
            p[r] = xa.x * wv0[r].x + xa.y * wv0[r].y + xa.z * wv0[r].z + xa.w * wv0[r].w
                 + xb.x * wv1[r].x + xb.y * wv1[r].y + xb.z * wv1[r].z + xb.w * wv1[r].w;
        }
        float A_ = merge_red(p[0], p[1], 1, lane);
        float Bm = merge_red(p[2], p[3], 1, lane);
        float C  = merge_red(p[4], p[5], 1, lane);
        float D_ = merge_red(A_, Bm, 2, lane);
        C += __shfl_xor(C, 2, 64);
        float E  = merge_red(D_, C, 4, lane);
        E += __shfl_xor(E, 8, 64);
        E += __shfl_xor(E, 16, 64);
        E += __shfl_xor(E, 32, 64);
        E += bv;

        float sq = (o < 6) ? E * E : 0.f;
        sq += __shfl_xor(sq, 1, 64);
        sq += __shfl_xor(sq, 2, 64);
        sq += __shfl_xor(sq, 4, 64);
        const float ang = 0.5f * E * rsqrtf(sq);
        float s_ang, c_ang;
        __sincosf(ang, &s_ang, &c_ang);

        float mag = 1.f;
        #pragma unroll
        for (int q = 0; q < NQ; ++q) {
            float cq  = bcastf(c_ang, q);
            float sq_ = bcastf(s_ang, q);
            mag *= ((lane >> (5 - q)) & 1) ? sq_ : cq;
        }
        // w[row=r16][k=lane] -> swizzled chunk ((lane>>3)^(r16&7)), halfword lane&7
        wp[r16 * 64 + (((lane >> 3) ^ (r16 & 7)) << 3) + (lane & 7)] = f2bf(mag);
    }

    // ---- phase B: S = w * U'^T via MFMA (M=16, N=64, K=64), re & im ----
    // A frag: A[m=lane&15][k=(lane>>4)*8+j];  B frag: B[k=(lane>>4)*8+j][n=lane&15]
    f32x4 cre[4] = {}, cim[4] = {};
    const int g4 = lane >> 4;
    const int lo3 = lane & 7;
    const short8 a0 = wtile[wave][lane & 15][(g4)     ^ lo3];
    const short8 a1 = wtile[wave][lane & 15][(4 + g4) ^ lo3];
    #pragma unroll
    for (int nt = 0; nt < 4; ++nt) {
        const int brow = nt * 16 + (lane & 15);
        const short8 br0 = Mlds[0][brow][(g4)     ^ lo3];
        const short8 br1 = Mlds[0][brow][(4 + g4) ^ lo3];
        const short8 bi0 = Mlds[1][brow][(g4)     ^ lo3];
        const short8 bi1 = Mlds[1][brow][(4 + g4) ^ lo3];
        cre[nt] = __builtin_amdgcn_mfma_f32_16x16x32_bf16(a0, br0, cre[nt], 0, 0, 0);
        cre[nt] = __builtin_amdgcn_mfma_f32_16x16x32_bf16(a1, br1, cre[nt], 0, 0, 0);
        cim[nt] = __builtin_amdgcn_mfma_f32_16x16x32_bf16(a0, bi0, cim[nt], 0, 0, 0);
        cim[nt] = __builtin_amdgcn_mfma_f32_16x16x32_bf16(a1, bi1, cim[nt], 0, 0, 0);
    }

    // ---- epilogue: probs, then 6 signed sums over n (C/D: col=lane&15,
    // row=(lane>>4)*4+reg; n = nt*16 + col; bits5,4 of n = nt; bits3..0 = col)
    const int col = lane & 15;
    #pragma unroll
    for (int reg = 0; reg < 4; ++reg) {
        const float p0 = cre[0][reg] * cre[0][reg] + cim[0][reg] * cim[0][reg];
        const float p1 = cre[1][reg] * cre[1][reg] + cim[1][reg] * cim[1][reg];
        const float p2 = cre[2][reg] * cre[2][reg] + cim[2][reg] * cim[2][reg];
        const float p3 = cre[3][reg] * cre[3][reg] + cim[3][reg] * cim[3][reg];
        float t  = (p0 + p1) + (p2 + p3);        // -> q2..q5 via WHT over col
        float y0 = (p0 + p1) - (p2 + p3);        // q0 (bit5 = nt>>1)
        float y1 = (p0 + p2) - (p1 + p3);        // q1 (bit4 = nt&1)
        #pragma unroll
        for (int m = 1; m <= 8; m <<= 1) {
            float rcv = __shfl_xor(t, m, 64);
            t = (lane & m) ? (rcv - t) : (t + rcv);
        }
        float y = merge_red(y0, y1, 1, lane);
        y += __shfl_xor(y, 2, 64);
        y += __shfl_xor(y, 4, 64);
        y += __shfl_xor(y, 8, 64);
        const size_t orow = (size_t)(rowbase + g4 * 4 + reg) * 6;
        if      (col == 0) { out[orow + 0] = y; }
        else if (col == 1) { out[orow + 1] = y; out[orow + 5] = t; }
        else if (col == 2) { out[orow + 4] = t; }
        else if (col == 4) { out[orow + 3] = t; }
        else if (col == 8) { out[orow + 2] = t; }
    }
}

extern "C" void kernel_launch(void* const* d_in, const int* in_sizes, int n_in,
                              void* d_out, int out_size, void* d_ws, size_t ws_size,
                              hipStream_t stream) {
    const float* x  = (const float*)d_in[0];
    const float* W  = (const float*)d_in[1];
    const float* bv = (const float*)d_in[2];
    const float* wt = (const float*)d_in[3];
    float* out = (float*)d_out;
    ushort* Mws = (ushort*)d_ws;            // 16 KB: U'_re then U'_im (bf16)
    const int B = in_sizes[0] / ROW_D;
    gen_unitary<<<16, 256, 0, stream>>>(wt, Mws);
    qmain<<<B / 64, 256, 0, stream>>>(x, W, bv, Mws, out, B);
}

// Round 4
// 37.570 us; speedup vs baseline: 2.7888x; 1.0219x over previous
//
#include <hip/hip_runtime.h>
#include <math.h>

#define NQ 6
#define NLAYERS 2
#define ROW_D 512

typedef short short8 __attribute__((ext_vector_type(8)));   // 8 bf16 in 4 VGPRs
typedef float f32x4 __attribute__((ext_vector_type(4)));

__device__ __forceinline__ ushort f2bf(float f) {           // f32 -> bf16 (RNE)
    unsigned u = __float_as_uint(f);
    return (ushort)((u + 0x7fffu + ((u >> 16) & 1u)) >> 16);
}
__device__ __forceinline__ float bf2f(ushort h) {
    return __uint_as_float((unsigned)h << 16);
}
__device__ __forceinline__ float merge_red(float u, float v, int m, int lane) {
    float send = (lane & m) ? u : v;
    float recv = __shfl_xor(send, m, 64);
    return ((lane & m) ? v : u) + recv;
}

// ws layout (ushort): [0,4096) U'_re, [4096,8192) U'_im,
//                     [8192,16384) W_hi (16x512, rows 6..15 zero), [16384,24576) W_lo
__global__ __launch_bounds__(256) void gen_tables(
    const float* __restrict__ weights, const float* __restrict__ W,
    ushort* __restrict__ ws)
{
    const int tid = threadIdx.x;

    // ---- W -> bf16 hi/lo, padded to 16 rows (each thread: 2 elements) ----
    {
        const int base = (blockIdx.x * 256 + tid) * 2;
        #pragma unroll
        for (int e = 0; e < 2; ++e) {
            const int i = base + e;
            const int n = i >> 9;
            const float v = (n < NQ) ? W[(n << 9) | (i & 511)] : 0.f;
            const ushort hi = f2bf(v);
            const ushort lo = f2bf(v - bf2f(hi));
            ws[8192 + i]  = hi;
            ws[16384 + i] = lo;
        }
    }

    // ---- U' = Circuit * diag((-i)^popc(j)), one wave per basis column ----
    __shared__ __align__(16) float gmat[NLAYERS * NQ * 8];
    if (tid < NLAYERS * NQ) {
        float phi = weights[tid * 3 + 0];
        float th  = weights[tid * 3 + 1];
        float om  = weights[tid * 3 + 2];
        float st, ct, sA, cA, sB, cB;
        __sincosf(0.5f * th, &st, &ct);
        __sincosf(0.5f * (phi + om), &sA, &cA);
        __sincosf(0.5f * (phi - om), &sB, &cB);
        float* g = &gmat[tid * 8];
        g[0] =  cA * ct;  g[1] = -sA * ct;   // u00
        g[2] = -cB * st;  g[3] = -sB * st;   // u01
        g[4] =  cA * ct;  g[5] =  sA * ct;   // u11
        g[6] =  cB * st;  g[7] = -sB * st;   // u10
    }
    __syncthreads();

    const int lane = tid & 63;
    const int wave = tid >> 6;
    const int jj = blockIdx.x * 4 + wave;

    int srcA = lane;
    #pragma unroll
    for (int q = NQ - 1; q >= 0; --q) {
        const int t = (q + 1) % NQ;
        srcA ^= ((srcA >> (5 - q)) & 1) << (5 - t);
    }
    int srcB = lane;
    #pragma unroll
    for (int q = NQ - 1; q >= 0; --q) {
        const int t = (q + 2) % NQ;
        srcB ^= ((srcB >> (5 - q)) & 1) << (5 - t);
    }
    const int adA = srcA << 2, adB = srcB << 2;

    float sr = (lane == jj) ? 1.f : 0.f;
    float si = 0.f;
    #pragma unroll
    for (int l = 0; l < NLAYERS; ++l) {
        #pragma unroll
        for (int q = 0; q < NQ; ++q) {
            const int bp = 5 - q, m = 1 << bp;
            const int bit = (lane >> bp) & 1;
            const float4 g = *reinterpret_cast<const float4*>(
                &gmat[((l * NQ + q) << 3) + (bit << 2)]);
            float pr = __shfl_xor(sr, m, 64);
            float pi = __shfl_xor(si, m, 64);
            float nr = g.x * sr - g.y * si + g.z * pr - g.w * pi;
            float ni = g.x * si + g.y * sr + g.z * pi + g.w * pr;
            sr = nr; si = ni;
        }
        const int ad = (l == 0) ? adA : adB;
        sr = __int_as_float(__builtin_amdgcn_ds_bpermute(ad, __float_as_int(sr)));
        si = __int_as_float(__builtin_amdgcn_ds_bpermute(ad, __float_as_int(si)));
    }

    const int pc = __popc(jj) & 3;
    float r2, i2;
    if      (pc == 1) { r2 =  si; i2 = -sr; }
    else if (pc == 2) { r2 = -sr; i2 = -si; }
    else if (pc == 3) { r2 = -si; i2 =  sr; }
    else              { r2 =  sr; i2 =  si; }
    ws[lane * 64 + jj]        = f2bf(r2);
    ws[4096 + lane * 64 + jj] = f2bf(i2);
}

// ---------------- main kernel: all-MFMA pipeline ---------------------------
__global__ __launch_bounds__(256) void qmain(
    const float* __restrict__ x, const float* __restrict__ bvec,
    const ushort* __restrict__ ws, float* __restrict__ out, int B)
{
    __shared__ short8 Mlds[2][64][8];      // 16 KB  U' re/im, chunk-swizzled
    __shared__ short8 Wlds[2][16][64];     // 32 KB  W hi/lo,  chunk-swizzled
    __shared__ float2 trans[4][144];       // 4.5 KB sincos transpose (9/row pad)
    const int tid = threadIdx.x;

    // stage U' (1024 chunks) and W (2048 chunks) from ws
    const short8* mg = reinterpret_cast<const short8*>(ws);
    #pragma unroll
    for (int i = 0; i < 4; ++i) {
        const int idx = tid + i * 256;
        short8 v = mg[idx];
        const int mat = idx >> 9, row = (idx >> 3) & 63, c = idx & 7;
        Mlds[mat][row][c ^ (row & 7)] = v;
    }
    #pragma unroll
    for (int i = 0; i < 8; ++i) {
        const int idx = tid + i * 256;
        short8 v = mg[1024 + idx];
        const int mat = idx >> 10, n = (idx >> 6) & 15, c = idx & 63;
        Wlds[mat][n][c ^ (n & 7)] = v;
    }
    __syncthreads();

    const int lane = tid & 63;
    const int wave = tid >> 6;
    const int g  = lane >> 4;      // k-group
    const int l4 = lane & 15;      // A-frag row / B-frag col
    const int swz = l4 & 7;
    const int rowbase = blockIdx.x * 64 + wave * 16;

    // ---- z-GEMM: z[m][n] = sum_k x[m][k] * W[n][k]  (x bf16-hi, W hi+lo) --
    f32x4 zacc = {0.f, 0.f, 0.f, 0.f};
    const float* xrow = x + (size_t)(rowbase + l4) * ROW_D + g * 8;
    #pragma unroll 4
    for (int kt = 0; kt < 16; ++kt) {
        const float4 xa = *reinterpret_cast<const float4*>(xrow + kt * 32);
        const float4 xb = *reinterpret_cast<const float4*>(xrow + kt * 32 + 4);
        short8 af;
        af[0] = (short)f2bf(xa.x); af[1] = (short)f2bf(xa.y);
        af[2] = (short)f2bf(xa.z); af[3] = (short)f2bf(xa.w);
        af[4] = (short)f2bf(xb.x); af[5] = (short)f2bf(xb.y);
        af[6] = (short)f2bf(xb.z); af[7] = (short)f2bf(xb.w);
        const int ch = (kt * 4 + g) ^ swz;
        const short8 bh = Wlds[0][l4][ch];
        const short8 bl = Wlds[1][l4][ch];
        zacc = __builtin_amdgcn_mfma_f32_16x16x32_bf16(af, bh, zacc, 0, 0, 0);
        zacc = __builtin_amdgcn_mfma_f32_16x16x32_bf16(af, bl, zacc, 0, 0, 0);
    }

    // ---- bias, per-row norm (in-group shuffles), sincos, transpose -------
    // C/D: lane holds z[m = g*4+reg][n = l4]; rows n>=6 of W are zero.
    const float bn = (l4 < NQ) ? bvec[l4] : 0.f;
    #pragma unroll
    for (int reg = 0; reg < 4; ++reg) {
        const float zv = zacc[reg] + bn;          // n>=6: 0+0
        float s2 = zv * zv;
        s2 += __shfl_xor(s2, 1, 64);
        s2 += __shfl_xor(s2, 2, 64);
        s2 += __shfl_xor(s2, 4, 64);
        s2 += __shfl_xor(s2, 8, 64);
        const float ang = 0.5f * zv * rsqrtf(s2);
        float sv, cv;
        __sincosf(ang, &sv, &cv);
        if (l4 < NQ)
            trans[wave][(g * 4 + reg) * 9 + l4] = make_float2(cv, sv);
    }

    // ---- gather this lane's row (m = l4) factors, build w A-frags --------
    float cq[NQ], sq[NQ];
    #pragma unroll
    for (int q = 0; q < NQ; ++q) {
        const float2 cs = trans[wave][l4 * 9 + q];
        cq[q] = cs.x; sq[q] = cs.y;
    }
    // w[k] = prod_q (bit_q(k) ? s_q : c_q);  k = {g*8+j, 32+g*8+j}
    float m45[4];
    m45[0] = cq[4] * cq[5]; m45[1] = cq[4] * sq[5];
    m45[2] = sq[4] * cq[5]; m45[3] = sq[4] * sq[5];
    float pl[8];
    #pragma unroll
    for (int j = 0; j < 8; ++j)
        pl[j] = ((j & 4) ? sq[3] : cq[3]) * m45[j & 3];
    const float t12 = ((g & 2) ? sq[1] : cq[1]) * ((g & 1) ? sq[2] : cq[2]);
    const float ph0 = cq[0] * t12;                 // khi = g   (bit q0 = 0)
    const float ph1 = sq[0] * t12;                 // khi = g+4 (bit q0 = 1)
    short8 a0, a1;
    #pragma unroll
    for (int j = 0; j < 8; ++j) {
        a0[j] = (short)f2bf(ph0 * pl[j]);
        a1[j] = (short)f2bf(ph1 * pl[j]);
    }

    // ---- S-GEMM: S = w * U'^T (M=16,N=64,K=64), re & im ------------------
    f32x4 cre[4] = {}, cim[4] = {};
    #pragma unroll
    for (int nt = 0; nt < 4; ++nt) {
        const int brow = nt * 16 + l4;
        const short8 br0 = Mlds[0][brow][(g)     ^ swz];
        const short8 br1 = Mlds[0][brow][(4 + g) ^ swz];
        const short8 bi0 = Mlds[1][brow][(g)     ^ swz];
        const short8 bi1 = Mlds[1][brow][(4 + g) ^ swz];
        cre[nt] = __builtin_amdgcn_mfma_f32_16x16x32_bf16(a0, br0, cre[nt], 0, 0, 0);
        cre[nt] = __builtin_amdgcn_mfma_f32_16x16x32_bf16(a1, br1, cre[nt], 0, 0, 0);
        cim[nt] = __builtin_amdgcn_mfma_f32_16x16x32_bf16(a0, bi0, cim[nt], 0, 0, 0);
        cim[nt] = __builtin_amdgcn_mfma_f32_16x16x32_bf16(a1, bi1, cim[nt], 0, 0, 0);
    }

    // ---- epilogue: probs -> 6 signed sums (WHT over n) -------------------
    const int col = l4;
    #pragma unroll
    for (int reg = 0; reg < 4; ++reg) {
        const float p0 = cre[0][reg] * cre[0][reg] + cim[0][reg] * cim[0][reg];
        const float p1 = cre[1][reg] * cre[1][reg] + cim[1][reg] * cim[1][reg];
        const float p2 = cre[2][reg] * cre[2][reg] + cim[2][reg] * cim[2][reg];
        const float p3 = cre[3][reg] * cre[3][reg] + cim[3][reg] * cim[3][reg];
        float t  = (p0 + p1) + (p2 + p3);        // -> q2..q5 via WHT over col
        float y0 = (p0 + p1) - (p2 + p3);        // q0 (bit5 = nt>>1)
        float y1 = (p0 + p2) - (p1 + p3);        // q1 (bit4 = nt&1)
        #pragma unroll
        for (int m = 1; m <= 8; m <<= 1) {
            float rcv = __shfl_xor(t, m, 64);
            t = (lane & m) ? (rcv - t) : (t + rcv);
        }
        float y = merge_red(y0, y1, 1, lane);
        y += __shfl_xor(y, 2, 64);
        y += __shfl_xor(y, 4, 64);
        y += __shfl_xor(y, 8, 64);
        const size_t orow = (size_t)(rowbase + g * 4 + reg) * 6;
        if      (col == 0) { out[orow + 0] = y; }
        else if (col == 1) { out[orow + 1] = y; out[orow + 5] = t; }
        else if (col == 2) { out[orow + 4] = t; }
        else if (col == 4) { out[orow + 3] = t; }
        else if (col == 8) { out[orow + 2] = t; }
    }
}

extern "C" void kernel_launch(void* const* d_in, const int* in_sizes, int n_in,
                              void* d_out, int out_size, void* d_ws, size_t ws_size,
                              hipStream_t stream) {
    const float* x  = (const float*)d_in[0];
    const float* W  = (const float*)d_in[1];
    const float* bv = (const float*)d_in[2];
    const float* wt = (const float*)d_in[3];
    float* out = (float*)d_out;
    ushort* ws = (ushort*)d_ws;             // 48 KB of tables
    const int B = in_sizes[0] / ROW_D;
    gen_tables<<<16, 256, 0, stream>>>(wt, W, ws);
    qmain<<<B / 64, 256, 0, stream>>>(x, bv, ws, out, B);
}

// Round 5
// 37.524 us; speedup vs baseline: 2.7922x; 1.0012x over previous
//
#include <hip/hip_runtime.h>
#include <math.h>

#define NQ 6
#define NLAYERS 2
#define ROW_D 512

typedef short short8 __attribute__((ext_vector_type(8)));   // 8 bf16 in 4 VGPRs
typedef float f32x4 __attribute__((ext_vector_type(4)));

__device__ __forceinline__ ushort f2bf(float f) {           // f32 -> bf16 (RNE)
    unsigned u = __float_as_uint(f);
    return (ushort)((u + 0x7fffu + ((u >> 16) & 1u)) >> 16);
}
__device__ __forceinline__ float bf2f(ushort h) {
    return __uint_as_float((unsigned)h << 16);
}
__device__ __forceinline__ float merge_red(float u, float v, int m, int lane) {
    float send = (lane & m) ? u : v;
    float recv = __shfl_xor(send, m, 64);
    return ((lane & m) ? v : u) + recv;
}

// ws layout (ushort): [0,4096) U'_re, [4096,8192) U'_im,
// [8192,16384) W_packed 16x512: rows 0..5 = W_hi, rows 8..13 = W_lo, else 0
__global__ __launch_bounds__(256) void gen_tables(
    const float* __restrict__ weights, const float* __restrict__ W,
    ushort* __restrict__ ws)
{
    const int tid = threadIdx.x;

    // ---- W -> packed bf16 hi/lo tile (8192 ushorts, 2 per thread) ----
    {
        const int base = (blockIdx.x * 256 + tid) * 2;
        #pragma unroll
        for (int e = 0; e < 2; ++e) {
            const int i = base + e;
            const int n = i >> 9, k = i & 511;
            ushort v = 0;
            if (n < NQ) {
                v = f2bf(W[(n << 9) | k]);
            } else if (n >= 8 && n < 8 + NQ) {
                const float w = W[((n - 8) << 9) | k];
                v = f2bf(w - bf2f(f2bf(w)));
            }
            ws[8192 + i] = v;
        }
    }

    // ---- U' = Circuit * diag((-i)^popc(j)), one wave per basis column ----
    __shared__ __align__(16) float gmat[NLAYERS * NQ * 8];
    if (tid < NLAYERS * NQ) {
        float phi = weights[tid * 3 + 0];
        float th  = weights[tid * 3 + 1];
        float om  = weights[tid * 3 + 2];
        float st, ct, sA, cA, sB, cB;
        __sincosf(0.5f * th, &st, &ct);
        __sincosf(0.5f * (phi + om), &sA, &cA);
        __sincosf(0.5f * (phi - om), &sB, &cB);
        float* g = &gmat[tid * 8];
        g[0] =  cA * ct;  g[1] = -sA * ct;   // u00
        g[2] = -cB * st;  g[3] = -sB * st;   // u01
        g[4] =  cA * ct;  g[5] =  sA * ct;   // u11
        g[6] =  cB * st;  g[7] = -sB * st;   // u10
    }
    __syncthreads();

    const int lane = tid & 63;
    const int wave = tid >> 6;
    const int jj = blockIdx.x * 4 + wave;

    int srcA = lane;
    #pragma unroll
    for (int q = NQ - 1; q >= 0; --q) {
        const int t = (q + 1) % NQ;
        srcA ^= ((srcA >> (5 - q)) & 1) << (5 - t);
    }
    int srcB = lane;
    #pragma unroll
    for (int q = NQ - 1; q >= 0; --q) {
        const int t = (q + 2) % NQ;
        srcB ^= ((srcB >> (5 - q)) & 1) << (5 - t);
    }
    const int adA = srcA << 2, adB = srcB << 2;

    float sr = (lane == jj) ? 1.f : 0.f;
    float si = 0.f;
    #pragma unroll
    for (int l = 0; l < NLAYERS; ++l) {
        #pragma unroll
        for (int q = 0; q < NQ; ++q) {
            const int bp = 5 - q, m = 1 << bp;
            const int bit = (lane >> bp) & 1;
            const float4 g = *reinterpret_cast<const float4*>(
                &gmat[((l * NQ + q) << 3) + (bit << 2)]);
            float pr = __shfl_xor(sr, m, 64);
            float pi = __shfl_xor(si, m, 64);
            float nr = g.x * sr - g.y * si + g.z * pr - g.w * pi;
            float ni = g.x * si + g.y * sr + g.z * pi + g.w * pr;
            sr = nr; si = ni;
        }
        const int ad = (l == 0) ? adA : adB;
        sr = __int_as_float(__builtin_amdgcn_ds_bpermute(ad, __float_as_int(sr)));
        si = __int_as_float(__builtin_amdgcn_ds_bpermute(ad, __float_as_int(si)));
    }

    const int pc = __popc(jj) & 3;
    float r2, i2;
    if      (pc == 1) { r2 =  si; i2 = -sr; }
    else if (pc == 2) { r2 = -sr; i2 = -si; }
    else if (pc == 3) { r2 = -si; i2 =  sr; }
    else              { r2 =  sr; i2 =  si; }
    ws[lane * 64 + jj]        = f2bf(r2);
    ws[4096 + lane * 64 + jj] = f2bf(i2);
}

// ---------------- main kernel: all-MFMA pipeline ---------------------------
__global__ __launch_bounds__(256, 4) void qmain(
    const float* __restrict__ x, const float* __restrict__ bvec,
    const ushort* __restrict__ ws, float* __restrict__ out, int B)
{
    __shared__ short8 Mlds[2][64][8];      // 16 KB  U' re/im, chunk-swizzled
    __shared__ short8 Wlds[16][64];        // 16 KB  W packed hi/lo, swizzled
    __shared__ float2 trans[4][144];       // 4.5 KB sincos transpose
    const int tid = threadIdx.x;

    const short8* mg = reinterpret_cast<const short8*>(ws);
    #pragma unroll
    for (int i = 0; i < 4; ++i) {
        const int idx = tid + i * 256;                // U': 1024 chunks
        short8 v = mg[idx];
        const int mat = idx >> 9, row = (idx >> 3) & 63, c = idx & 7;
        Mlds[mat][row][c ^ (row & 7)] = v;
    }
    #pragma unroll
    for (int i = 0; i < 4; ++i) {
        const int idx = tid + i * 256;                // W: 1024 chunks
        short8 v = mg[1024 + idx];
        const int n = idx >> 6, c = idx & 63;
        Wlds[n][c ^ (n & 7)] = v;
    }
    __syncthreads();

    const int lane = tid & 63;
    const int wave = tid >> 6;
    const int g  = lane >> 4;      // k-group
    const int l4 = lane & 15;      // A-frag row / B-frag col
    const int swz = l4 & 7;
    const int rowbase = blockIdx.x * 64 + wave * 16;

    // ---- z-GEMM: one MFMA/kt; cols 0..5 = z_hi, cols 8..13 = z_lo --------
    f32x4 zacc = {0.f, 0.f, 0.f, 0.f};
    const float* xrow = x + (size_t)(rowbase + l4) * ROW_D + g * 8;
    #pragma unroll 8
    for (int kt = 0; kt < 16; ++kt) {
        const float4 xa = *reinterpret_cast<const float4*>(xrow + kt * 32);
        const float4 xb = *reinterpret_cast<const float4*>(xrow + kt * 32 + 4);
        short8 af;
        af[0] = (short)f2bf(xa.x); af[1] = (short)f2bf(xa.y);
        af[2] = (short)f2bf(xa.z); af[3] = (short)f2bf(xa.w);
        af[4] = (short)f2bf(xb.x); af[5] = (short)f2bf(xb.y);
        af[6] = (short)f2bf(xb.z); af[7] = (short)f2bf(xb.w);
        const short8 bw = Wlds[l4][(kt * 4 + g) ^ swz];
        zacc = __builtin_amdgcn_mfma_f32_16x16x32_bf16(af, bw, zacc, 0, 0, 0);
    }

    // ---- z = z_hi + z_lo, bias, norm, sincos, transpose ------------------
    const float bn = (l4 < NQ) ? bvec[l4] : 0.f;
    #pragma unroll
    for (int reg = 0; reg < 4; ++reg) {
        const float zlo = __shfl_xor(zacc[reg], 8, 64);
        const float zv = zacc[reg] + zlo + bn;    // valid where l4 < 6
        float s2 = (l4 < NQ) ? zv * zv : 0.f;
        s2 += __shfl_xor(s2, 1, 64);
        s2 += __shfl_xor(s2, 2, 64);
        s2 += __shfl_xor(s2, 4, 64);
        s2 += __shfl_xor(s2, 8, 64);
        const float ang = 0.5f * zv * rsqrtf(s2);
        float sv, cv;
        __sincosf(ang, &sv, &cv);
        if (l4 < NQ)
            trans[wave][(g * 4 + reg) * 9 + l4] = make_float2(cv, sv);
    }

    // ---- gather this lane's row (m = l4) factors, build w A-frags --------
    float cq[NQ], sq[NQ];
    #pragma unroll
    for (int q = 0; q < NQ; ++q) {
        const float2 cs = trans[wave][l4 * 9 + q];
        cq[q] = cs.x; sq[q] = cs.y;
    }
    float m45[4];
    m45[0] = cq[4] * cq[5]; m45[1] = cq[4] * sq[5];
    m45[2] = sq[4] * cq[5]; m45[3] = sq[4] * sq[5];
    float pl[8];
    #pragma unroll
    for (int j = 0; j < 8; ++j)
        pl[j] = ((j & 4) ? sq[3] : cq[3]) * m45[j & 3];
    const float t12 = ((g & 2) ? sq[1] : cq[1]) * ((g & 1) ? sq[2] : cq[2]);
    const float ph0 = cq[0] * t12;                 // khi = g   (bit q0 = 0)
    const float ph1 = sq[0] * t12;                 // khi = g+4 (bit q0 = 1)
    short8 a0, a1;
    #pragma unroll
    for (int j = 0; j < 8; ++j) {
        a0[j] = (short)f2bf(ph0 * pl[j]);
        a1[j] = (short)f2bf(ph1 * pl[j]);
    }

    // ---- S-GEMM: S = w * U'^T (M=16,N=64,K=64), re & im ------------------
    f32x4 cre[4] = {}, cim[4] = {};
    #pragma unroll
    for (int nt = 0; nt < 4; ++nt) {
        const int brow = nt * 16 + l4;
        const short8 br0 = Mlds[0][brow][(g)     ^ swz];
        const short8 br1 = Mlds[0][brow][(4 + g) ^ swz];
        const short8 bi0 = Mlds[1][brow][(g)     ^ swz];
        const short8 bi1 = Mlds[1][brow][(4 + g) ^ swz];
        cre[nt] = __builtin_amdgcn_mfma_f32_16x16x32_bf16(a0, br0, cre[nt], 0, 0, 0);
        cre[nt] = __builtin_amdgcn_mfma_f32_16x16x32_bf16(a1, br1, cre[nt], 0, 0, 0);
        cim[nt] = __builtin_amdgcn_mfma_f32_16x16x32_bf16(a0, bi0, cim[nt], 0, 0, 0);
        cim[nt] = __builtin_amdgcn_mfma_f32_16x16x32_bf16(a1, bi1, cim[nt], 0, 0, 0);
    }

    // ---- epilogue: probs -> 6 signed sums (WHT over n) -------------------
    const int col = l4;
    #pragma unroll
    for (int reg = 0; reg < 4; ++reg) {
        const float p0 = cre[0][reg] * cre[0][reg] + cim[0][reg] * cim[0][reg];
        const float p1 = cre[1][reg] * cre[1][reg] + cim[1][reg] * cim[1][reg];
        const float p2 = cre[2][reg] * cre[2][reg] + cim[2][reg] * cim[2][reg];
        const float p3 = cre[3][reg] * cre[3][reg] + cim[3][reg] * cim[3][reg];
        float t  = (p0 + p1) + (p2 + p3);        // -> q2..q5 via WHT over col
        float y0 = (p0 + p1) - (p2 + p3);        // q0 (bit5 = nt>>1)
        float y1 = (p0 + p2) - (p1 + p3);        // q1 (bit4 = nt&1)
        #pragma unroll
        for (int m = 1; m <= 8; m <<= 1) {
            float rcv = __shfl_xor(t, m, 64);
            t = (lane & m) ? (rcv - t) : (t + rcv);
        }
        float y = merge_red(y0, y1, 1, lane);
        y += __shfl_xor(y, 2, 64);
        y += __shfl_xor(y, 4, 64);
        y += __shfl_xor(y, 8, 64);
        const size_t orow = (size_t)(rowbase + g * 4 + reg) * 6;
        if      (col == 0) { out[orow + 0] = y; }
        else if (col == 1) { out[orow + 1] = y; out[orow + 5] = t; }
        else if (col == 2) { out[orow + 4] = t; }
        else if (col == 4) { out[orow + 3] = t; }
        else if (col == 8) { out[orow + 2] = t; }
    }
}

extern "C" void kernel_launch(void* const* d_in, const int* in_sizes, int n_in,
                              void* d_out, int out_size, void* d_ws, size_t ws_size,
                              hipStream_t stream) {
    const float* x  = (const float*)d_in[0];
    const float* W  = (const float*)d_in[1];
    const float* bv = (const float*)d_in[2];
    const float* wt = (const float*)d_in[3];
    float* out = (float*)d_out;
    ushort* ws = (ushort*)d_ws;             // 32 KB of tables
    const int B = in_sizes[0] / ROW_D;
    gen_tables<<<16, 256, 0, stream>>>(wt, W, ws);
    qmain<<<B / 64, 256, 0, stream>>>(x, bv, ws, out, B);
}